// Round 3
// baseline (723.114 us; speedup 1.0000x reference)
//
#include <hip/hip_runtime.h>
#include <hip/hip_bf16.h>
#include <math.h>

#define NN 100000
#define NE 1600000
#define DH 128
#define DOUT 32

#define NPB 32              // nodes per bucket
#define NB  3125            // 100000 / 32 exactly

// ---------- bf16 helpers ----------
__device__ __forceinline__ unsigned short f2bf(float f) {
  union { float f; unsigned int i; } v; v.f = f;
  unsigned int i = v.i;
  unsigned int r = (i + 0x7FFFu + ((i >> 16) & 1u)) >> 16;   // RNE
  return (unsigned short)r;
}
__device__ __forceinline__ float bflo(unsigned int u) {
  union { unsigned int i; float f; } v; v.i = u << 16; return v.f;
}
__device__ __forceinline__ float bfhi(unsigned int u) {
  union { unsigned int i; float f; } v; v.i = u & 0xFFFF0000u; return v.f;
}
__device__ __forceinline__ float bf1(unsigned short u) {
  union { unsigned int i; float f; } v; v.i = ((unsigned int)u) << 16; return v.f;
}

// ---------------- CSR build: bucketed counting sort ----------------
// A: bucket histogram (LDS-privatized)
__global__ __launch_bounds__(512) void k_bhist(const int* __restrict__ dst,
                                               int* __restrict__ bcnt) {
  __shared__ int h[NB];
  for (int i = threadIdx.x; i < NB; i += 512) h[i] = 0;
  __syncthreads();
  int stride = gridDim.x * 512;
  for (int e = blockIdx.x * 512 + threadIdx.x; e < NE; e += stride) {
    int d = dst[e];
    d = d < 0 ? 0 : (d >= NN ? NN - 1 : d);
    atomicAdd(&h[d >> 5], 1);
  }
  __syncthreads();
  for (int i = threadIdx.x; i < NB; i += 512) {
    int v = h[i];
    if (v) atomicAdd(&bcnt[i], v);
  }
}

// B: exclusive scan of 3125 bucket counts (single block, 1024 thr, 4 elems/thr)
__global__ __launch_bounds__(1024) void k_bscan(const int* __restrict__ bcnt,
                                                int* __restrict__ boff) {
  __shared__ int sd[1024];
  int t = threadIdx.x;
  int v[4]; int loc = 0;
  #pragma unroll
  for (int i = 0; i < 4; i++) {
    int idx = t * 4 + i;
    v[i] = (idx < NB) ? bcnt[idx] : 0;
    loc += v[i];
  }
  sd[t] = loc;
  __syncthreads();
  for (int st = 1; st < 1024; st <<= 1) {
    int x = (t >= st) ? sd[t - st] : 0;
    __syncthreads();
    sd[t] += x;
    __syncthreads();
  }
  int run = (t ? sd[t - 1] : 0);
  #pragma unroll
  for (int i = 0; i < 4; i++) {
    int idx = t * 4 + i;
    if (idx < NB) boff[idx] = run;
    run += v[i];
  }
  if (t == 1023) boff[NB] = sd[1023];
}

// C: scatter edges into bucket-sorted ebuf; packed (local<<17)|src
__global__ void k_bscatter(const int* __restrict__ src, const int* __restrict__ dst,
                           const int* __restrict__ boff, int* __restrict__ bcur,
                           unsigned int* __restrict__ ebuf) {
  int e = blockIdx.x * 256 + threadIdx.x;
  if (e < NE) {
    int d = dst[e];
    d = d < 0 ? 0 : (d >= NN ? NN - 1 : d);
    int s = src[e];
    s = s < 0 ? 0 : (s >= NN ? NN - 1 : s);
    int b = d >> 5;
    int p = boff[b] + atomicAdd(&bcur[b], 1);
    ebuf[p] = (((unsigned int)(d & 31)) << 17) | (unsigned int)s;
  }
}

// D: per-node counts from bucket slices (LDS histogram, no global atomics)
__global__ __launch_bounds__(64) void k_bcnt(const unsigned int* __restrict__ ebuf,
                                             const int* __restrict__ boff,
                                             int* __restrict__ cnt) {
  __shared__ int h[NPB];
  int b = blockIdx.x, t = threadIdx.x;
  if (t < NPB) h[t] = 0;
  __syncthreads();
  int beg = boff[b], end = boff[b + 1];
  for (int i = beg + t; i < end; i += 64) atomicAdd(&h[ebuf[i] >> 17], 1);
  __syncthreads();
  if (t < NPB) cnt[b * NPB + t] = h[t];
}

// E: fill csrsrc; per-bucket LDS cursors, writes land in a ~2KB contiguous region
__global__ __launch_bounds__(64) void k_bfill(const unsigned int* __restrict__ ebuf,
                                              const int* __restrict__ boff,
                                              const int* __restrict__ csroff,
                                              int* __restrict__ csrsrc) {
  __shared__ int curs[NPB];
  __shared__ int offs[NPB];
  int b = blockIdx.x, t = threadIdx.x;
  if (t < NPB) { curs[t] = 0; offs[t] = csroff[b * NPB + t]; }
  __syncthreads();
  int beg = boff[b], end = boff[b + 1];
  for (int i = beg + t; i < end; i += 64) {
    unsigned int e = ebuf[i];
    int local = e >> 17;
    int s = (int)(e & 0x1FFFFu);
    int pos = offs[local] + atomicAdd(&curs[local], 1);
    csrsrc[pos] = s;
  }
}

// ---------------- node-count scan (cnt -> csroff) ----------------
#define CHUNK 1024

__global__ void k_scan_sum(const int* __restrict__ cnt, int* __restrict__ parts) {
  __shared__ int sd[256];
  int b = blockIdx.x, t = threadIdx.x;
  int base = b * CHUNK;
  int s = 0;
  for (int i = t; i < CHUNK; i += 256) {
    int idx = base + i;
    s += (idx < NN) ? cnt[idx] : 0;
  }
  sd[t] = s;
  __syncthreads();
  for (int st = 128; st; st >>= 1) {
    if (t < st) sd[t] += sd[t + st];
    __syncthreads();
  }
  if (t == 0) parts[b] = sd[0];
}

__global__ void k_scan_top(int* __restrict__ parts, int nb, int* __restrict__ csroff) {
  __shared__ int sd[128];
  int t = threadIdx.x;
  int v = (t < nb) ? parts[t] : 0;
  sd[t] = v;
  __syncthreads();
  for (int st = 1; st < 128; st <<= 1) {
    int x = (t >= st) ? sd[t - st] : 0;
    __syncthreads();
    sd[t] += x;
    __syncthreads();
  }
  if (t < nb) parts[t] = sd[t] - v;          // exclusive
  if (t == nb - 1) csroff[NN] = sd[t];       // == NE
}

__global__ void k_scan_chunks(const int* __restrict__ cnt, const int* __restrict__ parts,
                              int* __restrict__ csroff) {
  __shared__ int sums[256];
  int b = blockIdx.x, t = threadIdx.x;
  int base = b * CHUNK;
  int v[4]; int loc = 0;
  #pragma unroll
  for (int i = 0; i < 4; i++) {
    int idx = base + t * 4 + i;
    v[i] = (idx < NN) ? cnt[idx] : 0;
    loc += v[i];
  }
  sums[t] = loc;
  __syncthreads();
  for (int st = 1; st < 256; st <<= 1) {
    int x = (t >= st) ? sums[t - st] : 0;
    __syncthreads();
    sums[t] += x;
    __syncthreads();
  }
  int run = (t ? sums[t - 1] : 0) + parts[b];
  #pragma unroll
  for (int i = 0; i < 4; i++) {
    int idx = base + t * 4 + i;
    if (idx < NN) csroff[idx] = run;
    run += v[i];
  }
}

__global__ void k_invdeg(const int* __restrict__ cnt, float* __restrict__ invd) {
  int i = blockIdx.x * 256 + threadIdx.x;
  if (i < NN) {
    int d = cnt[i];
    invd[i] = 1.0f / (float)(d < 1 ? 1 : d);
  }
}

// ---------------- GEMM: [NN,128] @ [128,128] (+bias) ----------------
__device__ __forceinline__ int wswz(int c) { return c + ((c >> 5) << 2); }

template <int BF16OUT>
__global__ __launch_bounds__(256) void k_gemm128_t(
    const float* __restrict__ A, const float* __restrict__ W,
    const float* __restrict__ bias, void* __restrict__ outp) {
  __shared__ float sW[16 * 140];
  __shared__ float sX[16 * 132];
  int tid = threadIdx.x;
  int nb  = blockIdx.x * 128;
  int tx = tid & 15, ty = tid >> 4;

  float acc[8][8];
  #pragma unroll
  for (int i = 0; i < 8; i++)
    #pragma unroll
    for (int j = 0; j < 8; j++) acc[i][j] = 0.0f;

  for (int kb = 0; kb < 8; kb++) {
    __syncthreads();
    #pragma unroll
    for (int i = 0; i < 2; i++) {
      int j = i * 256 + tid;
      int node = j >> 2;
      int k4 = (j & 3) * 4;
      float4 xv = make_float4(0.f, 0.f, 0.f, 0.f);
      int gn = nb + node;
      if (gn < NN) xv = *(const float4*)&A[gn * 128 + kb * 16 + k4];
      sX[(k4 + 0) * 132 + node] = xv.x;
      sX[(k4 + 1) * 132 + node] = xv.y;
      sX[(k4 + 2) * 132 + node] = xv.z;
      sX[(k4 + 3) * 132 + node] = xv.w;
    }
    #pragma unroll
    for (int i = 0; i < 2; i++) {
      int j = i * 256 + tid;
      int k = j >> 5;
      int c4 = (j & 31) * 4;
      float4 wv = *(const float4*)&W[(kb * 16 + k) * 128 + c4];
      *(float4*)&sW[k * 140 + wswz(c4)] = wv;
    }
    __syncthreads();
    #pragma unroll
    for (int kk = 0; kk < 16; kk++) {
      float4 xa = *(const float4*)&sX[kk * 132 + 8 * ty];
      float4 xb = *(const float4*)&sX[kk * 132 + 8 * ty + 4];
      int cb = 8 * tx;
      float4 wa = *(const float4*)&sW[kk * 140 + wswz(cb)];
      float4 wb = *(const float4*)&sW[kk * 140 + wswz(cb + 4)];
      float xv[8] = {xa.x, xa.y, xa.z, xa.w, xb.x, xb.y, xb.z, xb.w};
      float wv[8] = {wa.x, wa.y, wa.z, wa.w, wb.x, wb.y, wb.z, wb.w};
      #pragma unroll
      for (int i = 0; i < 8; i++)
        #pragma unroll
        for (int j = 0; j < 8; j++)
          acc[i][j] += xv[i] * wv[j];
    }
  }
  float bs[8];
  #pragma unroll
  for (int j = 0; j < 8; j++) bs[j] = bias ? bias[8 * tx + j] : 0.0f;
  #pragma unroll
  for (int i = 0; i < 8; i++) {
    int gn = nb + 8 * ty + i;
    if (gn < NN) {
      if (BF16OUT) {
        unsigned short* out = (unsigned short*)outp;
        union { unsigned short us[8]; uint4 v; } o;
        #pragma unroll
        for (int j = 0; j < 8; j++) o.us[j] = f2bf(acc[i][j] + bs[j]);
        *(uint4*)&out[gn * 128 + 8 * tx] = o.v;
      } else {
        float* out = (float*)outp;
        float4 o0 = make_float4(acc[i][0] + bs[0], acc[i][1] + bs[1],
                                acc[i][2] + bs[2], acc[i][3] + bs[3]);
        float4 o1 = make_float4(acc[i][4] + bs[4], acc[i][5] + bs[5],
                                acc[i][6] + bs[6], acc[i][7] + bs[7]);
        *(float4*)&out[gn * 128 + 8 * tx]     = o0;
        *(float4*)&out[gn * 128 + 8 * tx + 4] = o1;
      }
    }
  }
}

// ---------------- dual GEMM: [NN,128] @ [128,32] ----------------
__global__ __launch_bounds__(128) void k_gemm32(
    const float* __restrict__ A, const float* __restrict__ Wl,
    const float* __restrict__ Wr, const float* __restrict__ bias,
    unsigned short* __restrict__ yl, float* __restrict__ yr) {
  __shared__ float sAT[64 * 68];
  __shared__ float sWl[64 * 36];
  __shared__ float sWr[64 * 36];
  int tid = threadIdx.x;
  int nb  = blockIdx.x * 64;
  int ng = tid >> 3;
  int cg = tid & 7;

  float accl[4][4], accr[4][4];
  #pragma unroll
  for (int i = 0; i < 4; i++)
    #pragma unroll
    for (int j = 0; j < 4; j++) { accl[i][j] = 0.f; accr[i][j] = 0.f; }

  for (int kb = 0; kb < 2; kb++) {
    __syncthreads();
    #pragma unroll
    for (int i = 0; i < 8; i++) {
      int j = i * 128 + tid;
      int node = j >> 4;
      int k4 = (j & 15) * 4;
      float4 v = make_float4(0.f, 0.f, 0.f, 0.f);
      int gn = nb + node;
      if (gn < NN) v = *(const float4*)&A[gn * 128 + kb * 64 + k4];
      sAT[(k4 + 0) * 68 + node] = v.x;
      sAT[(k4 + 1) * 68 + node] = v.y;
      sAT[(k4 + 2) * 68 + node] = v.z;
      sAT[(k4 + 3) * 68 + node] = v.w;
    }
    #pragma unroll
    for (int i = 0; i < 4; i++) {
      int j = i * 128 + tid;
      int k = j >> 3;
      int c4 = (j & 7) * 4;
      *(float4*)&sWl[k * 36 + c4] = *(const float4*)&Wl[(kb * 64 + k) * 32 + c4];
      *(float4*)&sWr[k * 36 + c4] = *(const float4*)&Wr[(kb * 64 + k) * 32 + c4];
    }
    __syncthreads();
    #pragma unroll 8
    for (int kk = 0; kk < 64; kk++) {
      float4 a  = *(const float4*)&sAT[kk * 68 + 4 * ng];
      float4 wl = *(const float4*)&sWl[kk * 36 + 4 * cg];
      float4 wr = *(const float4*)&sWr[kk * 36 + 4 * cg];
      float av[4] = {a.x, a.y, a.z, a.w};
      float wlv[4] = {wl.x, wl.y, wl.z, wl.w};
      float wrv[4] = {wr.x, wr.y, wr.z, wr.w};
      #pragma unroll
      for (int i = 0; i < 4; i++)
        #pragma unroll
        for (int j = 0; j < 4; j++) {
          accl[i][j] += av[i] * wlv[j];
          accr[i][j] += av[i] * wrv[j];
        }
    }
  }
  float bs[4];
  #pragma unroll
  for (int j = 0; j < 4; j++) bs[j] = bias[4 * cg + j];
  #pragma unroll
  for (int i = 0; i < 4; i++) {
    int gn = nb + 4 * ng + i;
    if (gn < NN) {
      union { unsigned short us[4]; uint2 v; } o;
      #pragma unroll
      for (int j = 0; j < 4; j++) o.us[j] = f2bf(accl[i][j]);
      *(uint2*)&yl[gn * 32 + 4 * cg] = o.v;
      *(float4*)&yr[gn * 32 + 4 * cg] =
          make_float4(accr[i][0] + bs[0], accr[i][1] + bs[1],
                      accr[i][2] + bs[2], accr[i][3] + bs[3]);
    }
  }
}

// ---------------- pull aggregation, 128-dim (bf16 gather) ----------------
__global__ __launch_bounds__(256) void k_agg128(
    const unsigned short* __restrict__ yl, const float* __restrict__ yr,
    const int* __restrict__ off, const int* __restrict__ csr,
    const float* __restrict__ invd, float* __restrict__ out, int relu) {
  int wid  = (blockIdx.x * 256 + threadIdx.x) >> 6;
  int lane = threadIdx.x & 63;
  if (wid >= NN) return;
  int beg = off[wid], end = off[wid + 1];
  const unsigned int* ylp = (const unsigned int*)yl;
  float ax0 = 0.f, ay0 = 0.f, ax1 = 0.f, ay1 = 0.f;
  float ax2 = 0.f, ay2 = 0.f, ax3 = 0.f, ay3 = 0.f;
  int e = beg;
  for (; e + 3 < end; e += 4) {
    int s0 = csr[e], s1 = csr[e + 1], s2 = csr[e + 2], s3 = csr[e + 3];
    unsigned int u0 = ylp[s0 * 64 + lane];
    unsigned int u1 = ylp[s1 * 64 + lane];
    unsigned int u2 = ylp[s2 * 64 + lane];
    unsigned int u3 = ylp[s3 * 64 + lane];
    ax0 += bflo(u0); ay0 += bfhi(u0);
    ax1 += bflo(u1); ay1 += bfhi(u1);
    ax2 += bflo(u2); ay2 += bfhi(u2);
    ax3 += bflo(u3); ay3 += bfhi(u3);
  }
  for (; e < end; e++) {
    int s = csr[e];
    unsigned int u = ylp[s * 64 + lane];
    ax0 += bflo(u); ay0 += bfhi(u);
  }
  float sc = invd[wid];
  float2 r = ((const float2*)yr)[wid * 64 + lane];
  float vx = ((ax0 + ax1) + (ax2 + ax3)) * sc + r.x;
  float vy = ((ay0 + ay1) + (ay2 + ay3)) * sc + r.y;
  if (relu) { vx = fmaxf(vx, 0.f); vy = fmaxf(vy, 0.f); }
  ((float2*)out)[wid * 64 + lane] = make_float2(vx, vy);
}

// ---------------- 32-dim aggregation + bias + log_softmax ----------------
__global__ __launch_bounds__(256) void k_agg32_lsm(
    const unsigned short* __restrict__ yl, const float* __restrict__ yr,
    const int* __restrict__ off, const int* __restrict__ csr,
    const float* __restrict__ invd, float* __restrict__ out) {
  int row  = (blockIdx.x * 256 + threadIdx.x) >> 5;
  int lane = threadIdx.x & 31;
  if (row >= NN) return;
  int beg = off[row], end = off[row + 1];
  float a0 = 0.f, a1 = 0.f, a2 = 0.f, a3 = 0.f;
  int e = beg;
  for (; e + 3 < end; e += 4) {
    int s0 = csr[e], s1 = csr[e + 1], s2 = csr[e + 2], s3 = csr[e + 3];
    a0 += bf1(yl[s0 * 32 + lane]);
    a1 += bf1(yl[s1 * 32 + lane]);
    a2 += bf1(yl[s2 * 32 + lane]);
    a3 += bf1(yl[s3 * 32 + lane]);
  }
  for (; e < end; e++) a0 += bf1(yl[csr[e] * 32 + lane]);
  float v = ((a0 + a1) + (a2 + a3)) * invd[row] + yr[row * 32 + lane];
  float m = v;
  #pragma unroll
  for (int o = 16; o; o >>= 1) m = fmaxf(m, __shfl_xor(m, o, 32));
  float ex = expf(v - m);
  float s = ex;
  #pragma unroll
  for (int o = 16; o; o >>= 1) s += __shfl_xor(s, o, 32);
  out[row * 32 + lane] = v - m - logf(s);
}

// ---------------- launch ----------------

extern "C" void kernel_launch(void* const* d_in, const int* in_sizes, int n_in,
                              void* d_out, int out_size, void* d_ws, size_t ws_size,
                              hipStream_t stream) {
  (void)in_sizes; (void)n_in; (void)out_size; (void)ws_size;
  const float* x   = (const float*)d_in[0];
  const int*   ei  = (const int*)d_in[1];
  const float* Wl0 = (const float*)d_in[2];
  const float* bl0 = (const float*)d_in[3];
  const float* Wr0 = (const float*)d_in[4];
  const float* Wl1 = (const float*)d_in[5];
  const float* bl1 = (const float*)d_in[6];
  const float* Wr1 = (const float*)d_in[7];
  const float* Wl2 = (const float*)d_in[8];
  const float* bl2 = (const float*)d_in[9];
  const float* Wr2 = (const float*)d_in[10];
  const int* srcI = ei;
  const int* dstI = ei + NE;

  char* w = (char*)d_ws;
  int*   bcnt   = (int*)(w + 0);                       // 3125
  int*   bcur   = (int*)(w + (16 << 10));              // 3125
  int*   boff   = (int*)(w + (32 << 10));              // 3126
  int*   cnt    = (int*)(w + (64 << 10));              // 100000
  int*   csroff = (int*)(w + (512 << 10));             // 100001
  float* invd   = (float*)(w + (1024 << 10));          // 100000
  int*   parts  = (int*)(w + (1536 << 10));            // 128
  unsigned int* ebuf = (unsigned int*)(w + (size_t)(2) * 1024 * 1024);   // 6.4 MB
  int*   csrsrc = (int*)(w + (size_t)(9) * 1024 * 1024);                 // 6.4 MB
  unsigned short* ylb = (unsigned short*)(w + (size_t)(16) * 1024 * 1024); // 25.6 MB
  float* yr     = (float*)(w + (size_t)(48)  * 1024 * 1024);             // 51.2 MB
  float* hb     = (float*)(w + (size_t)(100) * 1024 * 1024);             // 51.2 MB

  hipMemsetAsync(bcnt, 0, NB * sizeof(int), stream);
  hipMemsetAsync(bcur, 0, NB * sizeof(int), stream);

  // CSR build (bucketed counting sort)
  k_bhist<<<80, 512, 0, stream>>>(dstI, bcnt);
  k_bscan<<<1, 1024, 0, stream>>>(bcnt, boff);
  k_bscatter<<<(NE + 255) / 256, 256, 0, stream>>>(srcI, dstI, boff, bcur, ebuf);
  k_bcnt<<<NB, 64, 0, stream>>>(ebuf, boff, cnt);
  int nch = (NN + CHUNK - 1) / CHUNK;   // 98
  k_scan_sum<<<nch, 256, 0, stream>>>(cnt, parts);
  k_scan_top<<<1, 128, 0, stream>>>(parts, nch, csroff);
  k_scan_chunks<<<nch, 256, 0, stream>>>(cnt, parts, csroff);
  k_invdeg<<<(NN + 255) / 256, 256, 0, stream>>>(cnt, invd);
  k_bfill<<<NB, 64, 0, stream>>>(ebuf, boff, csroff, csrsrc);

  dim3 gg((NN + 127) / 128);
  // layer 0
  k_gemm128_t<1><<<gg, 256, 0, stream>>>(x, Wl0, nullptr, ylb);
  k_gemm128_t<0><<<gg, 256, 0, stream>>>(x, Wr0, bl0, yr);
  k_agg128<<<(NN * 64) / 256, 256, 0, stream>>>(ylb, yr, csroff, csrsrc, invd, hb, 1);
  // layer 1
  k_gemm128_t<1><<<gg, 256, 0, stream>>>(hb, Wl1, nullptr, ylb);
  k_gemm128_t<0><<<gg, 256, 0, stream>>>(hb, Wr1, bl1, yr);
  k_agg128<<<(NN * 64) / 256, 256, 0, stream>>>(ylb, yr, csroff, csrsrc, invd, hb, 1);
  // layer 2 (transform-first, 32-dim aggregation) + fused log_softmax
  k_gemm32<<<(NN + 63) / 64, 128, 0, stream>>>(hb, Wl2, Wr2, bl2, ylb, yr);
  k_agg32_lsm<<<(NN * 32) / 256, 256, 0, stream>>>(ylb, yr, csroff, csrsrc, invd,
                                                   (float*)d_out);
}

// Round 4
// 603.142 us; speedup vs baseline: 1.1989x; 1.1989x over previous
//
#include <hip/hip_runtime.h>
#include <hip/hip_bf16.h>
#include <math.h>

#define NN 100000
#define NE 1600000
#define DH 128
#define DOUT 32

#define NCB 391             // coarse buckets of 256 nodes: ceil(100000/256)
#define EB  8192            // edges per scatter block
#define SCT 512             // scatter block threads

// ---------- bf16 helpers ----------
__device__ __forceinline__ unsigned short f2bf(float f) {
  union { float f; unsigned int i; } v; v.f = f;
  unsigned int i = v.i;
  unsigned int r = (i + 0x7FFFu + ((i >> 16) & 1u)) >> 16;   // RNE
  return (unsigned short)r;
}
__device__ __forceinline__ float bflo(unsigned int u) {
  union { unsigned int i; float f; } v; v.i = u << 16; return v.f;
}
__device__ __forceinline__ float bfhi(unsigned int u) {
  union { unsigned int i; float f; } v; v.i = u & 0xFFFF0000u; return v.f;
}
__device__ __forceinline__ float bf1(unsigned short u) {
  union { unsigned int i; float f; } v; v.i = ((unsigned int)u) << 16; return v.f;
}

// ---------------- CSR build: hierarchical counting sort ----------------
// A: coarse-bucket histogram (LDS-privatized; ~50k global atomics total)
__global__ __launch_bounds__(512) void k_chist(const int* __restrict__ dst,
                                               int* __restrict__ ccnt) {
  __shared__ int h[NCB];
  for (int i = threadIdx.x; i < NCB; i += 512) h[i] = 0;
  __syncthreads();
  int stride = gridDim.x * 512;
  for (int e = blockIdx.x * 512 + threadIdx.x; e < NE; e += stride) {
    int d = dst[e];
    d = d < 0 ? 0 : (d >= NN ? NN - 1 : d);
    atomicAdd(&h[d >> 8], 1);
  }
  __syncthreads();
  for (int i = threadIdx.x; i < NCB; i += 512) {
    int v = h[i];
    if (v) atomicAdd(&ccnt[i], v);
  }
}

// B: exclusive scan of 391 coarse counts (one block); also seeds csroff[NN]
__global__ __launch_bounds__(512) void k_cscan(const int* __restrict__ ccnt,
                                               int* __restrict__ cboff,
                                               int* __restrict__ csroff) {
  __shared__ int sd[512];
  int t = threadIdx.x;
  int v = (t < NCB) ? ccnt[t] : 0;
  sd[t] = v;
  __syncthreads();
  for (int st = 1; st < 512; st <<= 1) {
    int x = (t >= st) ? sd[t - st] : 0;
    __syncthreads();
    sd[t] += x;
    __syncthreads();
  }
  if (t < NCB) cboff[t] = sd[t] - v;         // exclusive
  if (t == NCB - 1) { cboff[NCB] = sd[t]; csroff[NN] = sd[t]; }  // == NE
}

// C: scatter edges into coarse-bucket-sorted ebuf.
//    LDS ranking (per-edge LDS atomic) + ONE global atomic per (block,bucket).
//    Writes are ~21-entry runs per bucket per block -> mostly full lines.
//    packed entry: (dst&255)<<17 | src   (src < 2^17)
__global__ __launch_bounds__(SCT) void k_cscatter(
    const int* __restrict__ src, const int* __restrict__ dst,
    const int* __restrict__ cboff, int* __restrict__ ccur,
    unsigned int* __restrict__ ebuf) {
  __shared__ int lh[NCB];
  unsigned int cbr[16], pv[16];
  int t = threadIdx.x;
  int base = blockIdx.x * EB;
  for (int i = t; i < NCB; i += SCT) lh[i] = 0;
  __syncthreads();
  #pragma unroll
  for (int i = 0; i < 16; i++) {
    int e = base + i * SCT + t;
    if (e < NE) {
      int d = dst[e];
      d = d < 0 ? 0 : (d >= NN ? NN - 1 : d);
      int s = src[e];
      s = s < 0 ? 0 : (s >= NN ? NN - 1 : s);
      int cb = d >> 8;
      int r = atomicAdd(&lh[cb], 1);                 // LDS atomic: fast
      cbr[i] = (((unsigned int)cb) << 13) | (unsigned int)r;   // r < 8192
      pv[i]  = (((unsigned int)(d & 255)) << 17) | (unsigned int)s;
    } else {
      cbr[i] = 0xFFFFFFFFu;
    }
  }
  __syncthreads();
  // reserve a contiguous run per bucket (one global atomic per touched bucket)
  for (int i = t; i < NCB; i += SCT) {
    int c = lh[i];
    int g = c ? atomicAdd(&ccur[i], c) : 0;
    lh[i] = cboff[i] + g;                            // repurpose as run base
  }
  __syncthreads();
  #pragma unroll
  for (int i = 0; i < 16; i++) {
    if (cbr[i] != 0xFFFFFFFFu) {
      int cb = cbr[i] >> 13;
      int r  = cbr[i] & 0x1FFF;
      ebuf[lh[cb] + r] = pv[i];
    }
  }
}

// D: per-coarse-bucket refine -> exact CSR + csroff + invd.
//    All traffic confined to a ~16KB contiguous region per block.
__global__ __launch_bounds__(256) void k_crefine(
    const unsigned int* __restrict__ ebuf, const int* __restrict__ cboff,
    int* __restrict__ csroff, float* __restrict__ invd,
    int* __restrict__ csrsrc) {
  __shared__ int lh[256], pos[256], cur[256];
  int b = blockIdx.x, t = threadIdx.x;
  lh[t] = 0; cur[t] = 0;
  __syncthreads();
  int beg = cboff[b], end = cboff[b + 1];
  for (int i = beg + t; i < end; i += 256) atomicAdd(&lh[ebuf[i] >> 17], 1);
  __syncthreads();
  int v = lh[t];
  pos[t] = v;
  __syncthreads();
  for (int st = 1; st < 256; st <<= 1) {
    int x = (t >= st) ? pos[t - st] : 0;
    __syncthreads();
    pos[t] += x;
    __syncthreads();
  }
  int nid = b * 256 + t;
  int mybase = cboff[b] + pos[t] - v;                // exclusive prefix
  if (nid < NN) {
    csroff[nid] = mybase;
    invd[nid] = 1.0f / (float)(v < 1 ? 1 : v);
  }
  __syncthreads();
  pos[t] = mybase;
  __syncthreads();
  for (int i = beg + t; i < end; i += 256) {
    unsigned int u = ebuf[i];
    int local = u >> 17;
    int r = atomicAdd(&cur[local], 1);
    csrsrc[pos[local] + r] = (int)(u & 0x1FFFFu);
  }
}

// ---------------- GEMM: [NN,128] @ [128,128] (+bias) ----------------
__device__ __forceinline__ int wswz(int c) { return c + ((c >> 5) << 2); }

template <int BF16OUT>
__global__ __launch_bounds__(256) void k_gemm128_t(
    const float* __restrict__ A, const float* __restrict__ W,
    const float* __restrict__ bias, void* __restrict__ outp) {
  __shared__ float sW[16 * 140];
  __shared__ float sX[16 * 132];
  int tid = threadIdx.x;
  int nb  = blockIdx.x * 128;
  int tx = tid & 15, ty = tid >> 4;

  float acc[8][8];
  #pragma unroll
  for (int i = 0; i < 8; i++)
    #pragma unroll
    for (int j = 0; j < 8; j++) acc[i][j] = 0.0f;

  for (int kb = 0; kb < 8; kb++) {
    __syncthreads();
    #pragma unroll
    for (int i = 0; i < 2; i++) {
      int j = i * 256 + tid;
      int node = j >> 2;
      int k4 = (j & 3) * 4;
      float4 xv = make_float4(0.f, 0.f, 0.f, 0.f);
      int gn = nb + node;
      if (gn < NN) xv = *(const float4*)&A[gn * 128 + kb * 16 + k4];
      sX[(k4 + 0) * 132 + node] = xv.x;
      sX[(k4 + 1) * 132 + node] = xv.y;
      sX[(k4 + 2) * 132 + node] = xv.z;
      sX[(k4 + 3) * 132 + node] = xv.w;
    }
    #pragma unroll
    for (int i = 0; i < 2; i++) {
      int j = i * 256 + tid;
      int k = j >> 5;
      int c4 = (j & 31) * 4;
      float4 wv = *(const float4*)&W[(kb * 16 + k) * 128 + c4];
      *(float4*)&sW[k * 140 + wswz(c4)] = wv;
    }
    __syncthreads();
    #pragma unroll
    for (int kk = 0; kk < 16; kk++) {
      float4 xa = *(const float4*)&sX[kk * 132 + 8 * ty];
      float4 xb = *(const float4*)&sX[kk * 132 + 8 * ty + 4];
      int cb = 8 * tx;
      float4 wa = *(const float4*)&sW[kk * 140 + wswz(cb)];
      float4 wb = *(const float4*)&sW[kk * 140 + wswz(cb + 4)];
      float xv[8] = {xa.x, xa.y, xa.z, xa.w, xb.x, xb.y, xb.z, xb.w};
      float wv[8] = {wa.x, wa.y, wa.z, wa.w, wb.x, wb.y, wb.z, wb.w};
      #pragma unroll
      for (int i = 0; i < 8; i++)
        #pragma unroll
        for (int j = 0; j < 8; j++)
          acc[i][j] += xv[i] * wv[j];
    }
  }
  float bs[8];
  #pragma unroll
  for (int j = 0; j < 8; j++) bs[j] = bias ? bias[8 * tx + j] : 0.0f;
  #pragma unroll
  for (int i = 0; i < 8; i++) {
    int gn = nb + 8 * ty + i;
    if (gn < NN) {
      if (BF16OUT) {
        unsigned short* out = (unsigned short*)outp;
        union { unsigned short us[8]; uint4 v; } o;
        #pragma unroll
        for (int j = 0; j < 8; j++) o.us[j] = f2bf(acc[i][j] + bs[j]);
        *(uint4*)&out[gn * 128 + 8 * tx] = o.v;
      } else {
        float* out = (float*)outp;
        float4 o0 = make_float4(acc[i][0] + bs[0], acc[i][1] + bs[1],
                                acc[i][2] + bs[2], acc[i][3] + bs[3]);
        float4 o1 = make_float4(acc[i][4] + bs[4], acc[i][5] + bs[5],
                                acc[i][6] + bs[6], acc[i][7] + bs[7]);
        *(float4*)&out[gn * 128 + 8 * tx]     = o0;
        *(float4*)&out[gn * 128 + 8 * tx + 4] = o1;
      }
    }
  }
}

// ---------------- dual GEMM: [NN,128] @ [128,32] ----------------
__global__ __launch_bounds__(128) void k_gemm32(
    const float* __restrict__ A, const float* __restrict__ Wl,
    const float* __restrict__ Wr, const float* __restrict__ bias,
    unsigned short* __restrict__ yl, float* __restrict__ yr) {
  __shared__ float sAT[64 * 68];
  __shared__ float sWl[64 * 36];
  __shared__ float sWr[64 * 36];
  int tid = threadIdx.x;
  int nb  = blockIdx.x * 64;
  int ng = tid >> 3;
  int cg = tid & 7;

  float accl[4][4], accr[4][4];
  #pragma unroll
  for (int i = 0; i < 4; i++)
    #pragma unroll
    for (int j = 0; j < 4; j++) { accl[i][j] = 0.f; accr[i][j] = 0.f; }

  for (int kb = 0; kb < 2; kb++) {
    __syncthreads();
    #pragma unroll
    for (int i = 0; i < 8; i++) {
      int j = i * 128 + tid;
      int node = j >> 4;
      int k4 = (j & 15) * 4;
      float4 v = make_float4(0.f, 0.f, 0.f, 0.f);
      int gn = nb + node;
      if (gn < NN) v = *(const float4*)&A[gn * 128 + kb * 64 + k4];
      sAT[(k4 + 0) * 68 + node] = v.x;
      sAT[(k4 + 1) * 68 + node] = v.y;
      sAT[(k4 + 2) * 68 + node] = v.z;
      sAT[(k4 + 3) * 68 + node] = v.w;
    }
    #pragma unroll
    for (int i = 0; i < 4; i++) {
      int j = i * 128 + tid;
      int k = j >> 3;
      int c4 = (j & 7) * 4;
      *(float4*)&sWl[k * 36 + c4] = *(const float4*)&Wl[(kb * 64 + k) * 32 + c4];
      *(float4*)&sWr[k * 36 + c4] = *(const float4*)&Wr[(kb * 64 + k) * 32 + c4];
    }
    __syncthreads();
    #pragma unroll 8
    for (int kk = 0; kk < 64; kk++) {
      float4 a  = *(const float4*)&sAT[kk * 68 + 4 * ng];
      float4 wl = *(const float4*)&sWl[kk * 36 + 4 * cg];
      float4 wr = *(const float4*)&sWr[kk * 36 + 4 * cg];
      float av[4] = {a.x, a.y, a.z, a.w};
      float wlv[4] = {wl.x, wl.y, wl.z, wl.w};
      float wrv[4] = {wr.x, wr.y, wr.z, wr.w};
      #pragma unroll
      for (int i = 0; i < 4; i++)
        #pragma unroll
        for (int j = 0; j < 4; j++) {
          accl[i][j] += av[i] * wlv[j];
          accr[i][j] += av[i] * wrv[j];
        }
    }
  }
  float bs[4];
  #pragma unroll
  for (int j = 0; j < 4; j++) bs[j] = bias[4 * cg + j];
  #pragma unroll
  for (int i = 0; i < 4; i++) {
    int gn = nb + 4 * ng + i;
    if (gn < NN) {
      union { unsigned short us[4]; uint2 v; } o;
      #pragma unroll
      for (int j = 0; j < 4; j++) o.us[j] = f2bf(accl[i][j]);
      *(uint2*)&yl[gn * 32 + 4 * cg] = o.v;
      *(float4*)&yr[gn * 32 + 4 * cg] =
          make_float4(accr[i][0] + bs[0], accr[i][1] + bs[1],
                      accr[i][2] + bs[2], accr[i][3] + bs[3]);
    }
  }
}

// ---------------- pull aggregation, 128-dim (bf16 gather, 8-deep unroll) ----------------
__global__ __launch_bounds__(256) void k_agg128(
    const unsigned short* __restrict__ yl, const float* __restrict__ yr,
    const int* __restrict__ off, const int* __restrict__ csr,
    const float* __restrict__ invd, float* __restrict__ out, int relu) {
  int wid  = (blockIdx.x * 256 + threadIdx.x) >> 6;
  int lane = threadIdx.x & 63;
  if (wid >= NN) return;
  int beg = off[wid], end = off[wid + 1];
  const unsigned int* ylp = (const unsigned int*)yl;
  float ax0 = 0.f, ay0 = 0.f, ax1 = 0.f, ay1 = 0.f;
  float ax2 = 0.f, ay2 = 0.f, ax3 = 0.f, ay3 = 0.f;
  int e = beg;
  for (; e + 7 < end; e += 8) {
    int s0 = csr[e],     s1 = csr[e + 1], s2 = csr[e + 2], s3 = csr[e + 3];
    int s4 = csr[e + 4], s5 = csr[e + 5], s6 = csr[e + 6], s7 = csr[e + 7];
    unsigned int u0 = ylp[s0 * 64 + lane];
    unsigned int u1 = ylp[s1 * 64 + lane];
    unsigned int u2 = ylp[s2 * 64 + lane];
    unsigned int u3 = ylp[s3 * 64 + lane];
    unsigned int u4 = ylp[s4 * 64 + lane];
    unsigned int u5 = ylp[s5 * 64 + lane];
    unsigned int u6 = ylp[s6 * 64 + lane];
    unsigned int u7 = ylp[s7 * 64 + lane];
    ax0 += bflo(u0); ay0 += bfhi(u0);
    ax1 += bflo(u1); ay1 += bfhi(u1);
    ax2 += bflo(u2); ay2 += bfhi(u2);
    ax3 += bflo(u3); ay3 += bfhi(u3);
    ax0 += bflo(u4); ay0 += bfhi(u4);
    ax1 += bflo(u5); ay1 += bfhi(u5);
    ax2 += bflo(u6); ay2 += bfhi(u6);
    ax3 += bflo(u7); ay3 += bfhi(u7);
  }
  for (; e < end; e++) {
    int s = csr[e];
    unsigned int u = ylp[s * 64 + lane];
    ax0 += bflo(u); ay0 += bfhi(u);
  }
  float sc = invd[wid];
  float2 r = ((const float2*)yr)[wid * 64 + lane];
  float vx = ((ax0 + ax1) + (ax2 + ax3)) * sc + r.x;
  float vy = ((ay0 + ay1) + (ay2 + ay3)) * sc + r.y;
  if (relu) { vx = fmaxf(vx, 0.f); vy = fmaxf(vy, 0.f); }
  ((float2*)out)[wid * 64 + lane] = make_float2(vx, vy);
}

// ---------------- 32-dim aggregation + bias + log_softmax ----------------
__global__ __launch_bounds__(256) void k_agg32_lsm(
    const unsigned short* __restrict__ yl, const float* __restrict__ yr,
    const int* __restrict__ off, const int* __restrict__ csr,
    const float* __restrict__ invd, float* __restrict__ out) {
  int row  = (blockIdx.x * 256 + threadIdx.x) >> 5;
  int lane = threadIdx.x & 31;
  if (row >= NN) return;
  int beg = off[row], end = off[row + 1];
  float a0 = 0.f, a1 = 0.f, a2 = 0.f, a3 = 0.f;
  int e = beg;
  for (; e + 3 < end; e += 4) {
    int s0 = csr[e], s1 = csr[e + 1], s2 = csr[e + 2], s3 = csr[e + 3];
    a0 += bf1(yl[s0 * 32 + lane]);
    a1 += bf1(yl[s1 * 32 + lane]);
    a2 += bf1(yl[s2 * 32 + lane]);
    a3 += bf1(yl[s3 * 32 + lane]);
  }
  for (; e < end; e++) a0 += bf1(yl[csr[e] * 32 + lane]);
  float v = ((a0 + a1) + (a2 + a3)) * invd[row] + yr[row * 32 + lane];
  float m = v;
  #pragma unroll
  for (int o = 16; o; o >>= 1) m = fmaxf(m, __shfl_xor(m, o, 32));
  float ex = expf(v - m);
  float s = ex;
  #pragma unroll
  for (int o = 16; o; o >>= 1) s += __shfl_xor(s, o, 32);
  out[row * 32 + lane] = v - m - logf(s);
}

// ---------------- launch ----------------

extern "C" void kernel_launch(void* const* d_in, const int* in_sizes, int n_in,
                              void* d_out, int out_size, void* d_ws, size_t ws_size,
                              hipStream_t stream) {
  (void)in_sizes; (void)n_in; (void)out_size; (void)ws_size;
  const float* x   = (const float*)d_in[0];
  const int*   ei  = (const int*)d_in[1];
  const float* Wl0 = (const float*)d_in[2];
  const float* bl0 = (const float*)d_in[3];
  const float* Wr0 = (const float*)d_in[4];
  const float* Wl1 = (const float*)d_in[5];
  const float* bl1 = (const float*)d_in[6];
  const float* Wr1 = (const float*)d_in[7];
  const float* Wl2 = (const float*)d_in[8];
  const float* bl2 = (const float*)d_in[9];
  const float* Wr2 = (const float*)d_in[10];
  const int* srcI = ei;
  const int* dstI = ei + NE;

  char* w = (char*)d_ws;
  int*   ccnt   = (int*)(w + 0);                       // 391
  int*   ccur   = (int*)(w + (16 << 10));              // 391
  int*   cboff  = (int*)(w + (32 << 10));              // 392
  int*   csroff = (int*)(w + (512 << 10));             // 100001
  float* invd   = (float*)(w + (1024 << 10));          // 100000
  unsigned int* ebuf = (unsigned int*)(w + (size_t)(2) * 1024 * 1024);   // 6.4 MB
  int*   csrsrc = (int*)(w + (size_t)(9) * 1024 * 1024);                 // 6.4 MB
  unsigned short* ylb = (unsigned short*)(w + (size_t)(16) * 1024 * 1024); // 25.6 MB
  float* yr     = (float*)(w + (size_t)(48)  * 1024 * 1024);             // 51.2 MB
  float* hb     = (float*)(w + (size_t)(100) * 1024 * 1024);             // 51.2 MB

  hipMemsetAsync(ccnt, 0, NCB * sizeof(int), stream);
  hipMemsetAsync(ccur, 0, NCB * sizeof(int), stream);

  // CSR build (hierarchical counting sort: block-reserved runs, no per-edge
  // global atomics)
  k_chist<<<128, 512, 0, stream>>>(dstI, ccnt);
  k_cscan<<<1, 512, 0, stream>>>(ccnt, cboff, csroff);
  k_cscatter<<<(NE + EB - 1) / EB, SCT, 0, stream>>>(srcI, dstI, cboff, ccur, ebuf);
  k_crefine<<<NCB, 256, 0, stream>>>(ebuf, cboff, csroff, invd, csrsrc);

  dim3 gg((NN + 127) / 128);
  // layer 0
  k_gemm128_t<1><<<gg, 256, 0, stream>>>(x, Wl0, nullptr, ylb);
  k_gemm128_t<0><<<gg, 256, 0, stream>>>(x, Wr0, bl0, yr);
  k_agg128<<<(NN * 64) / 256, 256, 0, stream>>>(ylb, yr, csroff, csrsrc, invd, hb, 1);
  // layer 1
  k_gemm128_t<1><<<gg, 256, 0, stream>>>(hb, Wl1, nullptr, ylb);
  k_gemm128_t<0><<<gg, 256, 0, stream>>>(hb, Wr1, bl1, yr);
  k_agg128<<<(NN * 64) / 256, 256, 0, stream>>>(ylb, yr, csroff, csrsrc, invd, hb, 1);
  // layer 2 (transform-first, 32-dim aggregation) + fused log_softmax
  k_gemm32<<<(NN + 63) / 64, 128, 0, stream>>>(hb, Wl2, Wr2, bl2, ylb, yr);
  k_agg32_lsm<<<(NN * 32) / 256, 256, 0, stream>>>(ylb, yr, csroff, csrsrc, invd,
                                                   (float*)d_out);
}

// Round 5
// 485.355 us; speedup vs baseline: 1.4899x; 1.2427x over previous
//
#include <hip/hip_runtime.h>
#include <hip/hip_bf16.h>
#include <math.h>

#define NN 100000
#define NE 1600000

#define NCB 391             // coarse buckets of 256 nodes
#define EB  8192            // edges per scatter block
#define SCT 512             // scatter block threads

typedef __attribute__((ext_vector_type(8))) short short8;
typedef __attribute__((ext_vector_type(4))) float f32x4;

// ---------- bf16 helpers ----------
__device__ __forceinline__ unsigned short f2bf(float f) {
  union { float f; unsigned int i; } v; v.f = f;
  unsigned int i = v.i;
  unsigned int r = (i + 0x7FFFu + ((i >> 16) & 1u)) >> 16;   // RNE
  return (unsigned short)r;
}
__device__ __forceinline__ float bflo(unsigned int u) {
  union { unsigned int i; float f; } v; v.i = u << 16; return v.f;
}
__device__ __forceinline__ float bfhi(unsigned int u) {
  union { unsigned int i; float f; } v; v.i = u & 0xFFFF0000u; return v.f;
}
__device__ __forceinline__ float bf1(unsigned short u) {
  union { unsigned int i; float f; } v; v.i = ((unsigned int)u) << 16; return v.f;
}

// ---------------- CSR build: hierarchical counting sort (round-4, works) ----------------
__global__ __launch_bounds__(512) void k_chist(const int* __restrict__ dst,
                                               int* __restrict__ ccnt) {
  __shared__ int h[NCB];
  for (int i = threadIdx.x; i < NCB; i += 512) h[i] = 0;
  __syncthreads();
  int stride = gridDim.x * 512;
  for (int e = blockIdx.x * 512 + threadIdx.x; e < NE; e += stride) {
    int d = dst[e];
    d = d < 0 ? 0 : (d >= NN ? NN - 1 : d);
    atomicAdd(&h[d >> 8], 1);
  }
  __syncthreads();
  for (int i = threadIdx.x; i < NCB; i += 512) {
    int v = h[i];
    if (v) atomicAdd(&ccnt[i], v);
  }
}

__global__ __launch_bounds__(512) void k_cscan(const int* __restrict__ ccnt,
                                               int* __restrict__ cboff,
                                               int* __restrict__ csroff) {
  __shared__ int sd[512];
  int t = threadIdx.x;
  int v = (t < NCB) ? ccnt[t] : 0;
  sd[t] = v;
  __syncthreads();
  for (int st = 1; st < 512; st <<= 1) {
    int x = (t >= st) ? sd[t - st] : 0;
    __syncthreads();
    sd[t] += x;
    __syncthreads();
  }
  if (t < NCB) cboff[t] = sd[t] - v;
  if (t == NCB - 1) { cboff[NCB] = sd[t]; csroff[NN] = sd[t]; }
}

__global__ __launch_bounds__(SCT) void k_cscatter(
    const int* __restrict__ src, const int* __restrict__ dst,
    const int* __restrict__ cboff, int* __restrict__ ccur,
    unsigned int* __restrict__ ebuf) {
  __shared__ int lh[NCB];
  unsigned int cbr[16], pv[16];
  int t = threadIdx.x;
  int base = blockIdx.x * EB;
  for (int i = t; i < NCB; i += SCT) lh[i] = 0;
  __syncthreads();
  #pragma unroll
  for (int i = 0; i < 16; i++) {
    int e = base + i * SCT + t;
    if (e < NE) {
      int d = dst[e];
      d = d < 0 ? 0 : (d >= NN ? NN - 1 : d);
      int s = src[e];
      s = s < 0 ? 0 : (s >= NN ? NN - 1 : s);
      int cb = d >> 8;
      int r = atomicAdd(&lh[cb], 1);
      cbr[i] = (((unsigned int)cb) << 13) | (unsigned int)r;
      pv[i]  = (((unsigned int)(d & 255)) << 17) | (unsigned int)s;
    } else {
      cbr[i] = 0xFFFFFFFFu;
    }
  }
  __syncthreads();
  for (int i = t; i < NCB; i += SCT) {
    int c = lh[i];
    int g = c ? atomicAdd(&ccur[i], c) : 0;
    lh[i] = cboff[i] + g;
  }
  __syncthreads();
  #pragma unroll
  for (int i = 0; i < 16; i++) {
    if (cbr[i] != 0xFFFFFFFFu) {
      int cb = cbr[i] >> 13;
      int r  = cbr[i] & 0x1FFF;
      ebuf[lh[cb] + r] = pv[i];
    }
  }
}

__global__ __launch_bounds__(256) void k_crefine(
    const unsigned int* __restrict__ ebuf, const int* __restrict__ cboff,
    int* __restrict__ csroff, float* __restrict__ invd,
    int* __restrict__ csrsrc) {
  __shared__ int lh[256], pos[256], cur[256];
  int b = blockIdx.x, t = threadIdx.x;
  lh[t] = 0; cur[t] = 0;
  __syncthreads();
  int beg = cboff[b], end = cboff[b + 1];
  for (int i = beg + t; i < end; i += 256) atomicAdd(&lh[ebuf[i] >> 17], 1);
  __syncthreads();
  int v = lh[t];
  pos[t] = v;
  __syncthreads();
  for (int st = 1; st < 256; st <<= 1) {
    int x = (t >= st) ? pos[t - st] : 0;
    __syncthreads();
    pos[t] += x;
    __syncthreads();
  }
  int nid = b * 256 + t;
  int mybase = cboff[b] + pos[t] - v;
  if (nid < NN) {
    csroff[nid] = mybase;
    invd[nid] = 1.0f / (float)(v < 1 ? 1 : v);
  }
  __syncthreads();
  pos[t] = mybase;
  __syncthreads();
  for (int i = beg + t; i < end; i += 256) {
    unsigned int u = ebuf[i];
    int local = u >> 17;
    int r = atomicAdd(&cur[local], 1);
    csrsrc[pos[local] + r] = (int)(u & 0x1FFFFu);
  }
}

// ---------------- weight prep: W [128][nch] fp32 x2 -> B'[2*nch][128] bf16 ----------------
__global__ void k_wprep(const float* __restrict__ Wl, const float* __restrict__ Wr,
                        int nch, unsigned short* __restrict__ B) {
  int idx = blockIdx.x * 256 + threadIdx.x;
  int total = 2 * nch * 128;
  if (idx < total) {
    int n = idx >> 7;            // /128
    int k = idx & 127;
    float v = (n < nch) ? Wl[k * nch + n] : Wr[k * nch + (n - nch)];
    B[idx] = f2bf(v);
  }
}

// ---------------- MFMA GEMM: A[N,128] @ B'[NC,128]^T -> yl(NC/2 bf16) | yr(NC/2 bf16 +bias) ----
// Block: 512 thr (8 waves), M-tile 128 nodes, full-K (128) LDS staging.
// LDS rows padded to 136 bf16 (272 B): b128 reads land 2-way (free, m136).
// MFMA 16x16x32 bf16: A-frag A[m=lane&15][k=quad*8+j]; B-frag B[k][n=lane&15];
// C/D: col=lane&15, row=quad*4+reg (learn_hip m89/m91).
template <int NC, int AFP32>
__global__ __launch_bounds__(512) void k_mgemm(
    const void* __restrict__ Ap, const unsigned short* __restrict__ Bp,
    const float* __restrict__ bias,
    unsigned short* __restrict__ yl, unsigned short* __restrict__ yr) {
  __shared__ unsigned short sA[128 * 136];
  __shared__ unsigned short sB[NC * 136];
  int tid = threadIdx.x;
  int nb  = blockIdx.x * 128;

  // stage A
  if (AFP32) {
    const float* A = (const float*)Ap;
    #pragma unroll
    for (int i = 0; i < 8; i++) {
      int j = i * 512 + tid;            // 0..4095 float4s
      int m = j >> 5;
      int k4 = (j & 31) * 4;
      int gn = nb + m;
      float4 v = make_float4(0.f, 0.f, 0.f, 0.f);
      if (gn < NN) v = *(const float4*)&A[gn * 128 + k4];
      unsigned int p0 = (unsigned int)f2bf(v.x) | ((unsigned int)f2bf(v.y) << 16);
      unsigned int p1 = (unsigned int)f2bf(v.z) | ((unsigned int)f2bf(v.w) << 16);
      *(uint2*)&sA[m * 136 + k4] = make_uint2(p0, p1);
    }
  } else {
    const unsigned short* A = (const unsigned short*)Ap;
    #pragma unroll
    for (int i = 0; i < 4; i++) {
      int j = i * 512 + tid;            // 0..2047 16B-chunks
      int m = j >> 4;
      int k8 = (j & 15) * 8;
      int gn = nb + m;
      uint4 v = make_uint4(0, 0, 0, 0);
      if (gn < NN) v = *(const uint4*)&A[gn * 128 + k8];
      *(uint4*)&sA[m * 136 + k8] = v;
    }
  }
  // stage B'
  {
    int nchunks = NC * 16;
    for (int j = tid; j < nchunks; j += 512) {
      int n = j >> 4;
      int k8 = (j & 15) * 8;
      *(uint4*)&sB[n * 136 + k8] = *(const uint4*)&Bp[n * 128 + k8];
    }
  }
  __syncthreads();

  int wave = tid >> 6, lane = tid & 63;
  int l15 = lane & 15, lq = lane >> 4;
  constexpr int MT = (NC == 256) ? 4 : 2;
  constexpr int NT = (NC == 256) ? 4 : 2;
  int wm, wn;
  if (NC == 256) { wm = wave & 1; wn = wave >> 1; }
  else           { wm = wave >> 1; wn = wave & 1; }
  int mbase = wm * (MT * 16);
  int nbase = wn * (NT * 16);

  f32x4 acc[MT][NT];
  #pragma unroll
  for (int mi = 0; mi < MT; mi++)
    #pragma unroll
    for (int ni = 0; ni < NT; ni++) acc[mi][ni] = (f32x4){0.f, 0.f, 0.f, 0.f};

  #pragma unroll
  for (int kc = 0; kc < 4; kc++) {
    int k0 = kc * 32 + lq * 8;
    short8 af[MT], bfr[NT];
    #pragma unroll
    for (int mi = 0; mi < MT; mi++)
      af[mi] = *(const short8*)&sA[(mbase + mi * 16 + l15) * 136 + k0];
    #pragma unroll
    for (int ni = 0; ni < NT; ni++)
      bfr[ni] = *(const short8*)&sB[(nbase + ni * 16 + l15) * 136 + k0];
    #pragma unroll
    for (int mi = 0; mi < MT; mi++)
      #pragma unroll
      for (int ni = 0; ni < NT; ni++)
        acc[mi][ni] = __builtin_amdgcn_mfma_f32_16x16x32_bf16(
            af[mi], bfr[ni], acc[mi][ni], 0, 0, 0);
  }

  // epilogue
  constexpr int HC = NC / 2;
  #pragma unroll
  for (int mi = 0; mi < MT; mi++) {
    #pragma unroll
    for (int ni = 0; ni < NT; ni++) {
      int n = nbase + ni * 16 + l15;
      #pragma unroll
      for (int r = 0; r < 4; r++) {
        int gn = nb + mbase + mi * 16 + lq * 4 + r;
        if (gn < NN) {
          float v = acc[mi][ni][r];
          if (n < HC) {
            yl[(size_t)gn * HC + n] = f2bf(v);
          } else {
            int n2 = n - HC;
            yr[(size_t)gn * HC + n2] = f2bf(v + bias[n2]);
          }
        }
      }
    }
  }
}

// ---------------- pull aggregation, 128-dim (bf16 gather, bf16 out) ----------------
__global__ __launch_bounds__(256) void k_agg128(
    const unsigned short* __restrict__ yl, const unsigned short* __restrict__ yr,
    const int* __restrict__ off, const int* __restrict__ csr,
    const float* __restrict__ invd, unsigned short* __restrict__ out, int relu) {
  int wid  = (blockIdx.x * 256 + threadIdx.x) >> 6;
  int lane = threadIdx.x & 63;
  if (wid >= NN) return;
  int beg = off[wid], end = off[wid + 1];
  const unsigned int* ylp = (const unsigned int*)yl;
  float ax0 = 0.f, ay0 = 0.f, ax1 = 0.f, ay1 = 0.f;
  float ax2 = 0.f, ay2 = 0.f, ax3 = 0.f, ay3 = 0.f;
  int e = beg;
  for (; e + 7 < end; e += 8) {
    int s0 = csr[e],     s1 = csr[e + 1], s2 = csr[e + 2], s3 = csr[e + 3];
    int s4 = csr[e + 4], s5 = csr[e + 5], s6 = csr[e + 6], s7 = csr[e + 7];
    unsigned int u0 = ylp[s0 * 64 + lane];
    unsigned int u1 = ylp[s1 * 64 + lane];
    unsigned int u2 = ylp[s2 * 64 + lane];
    unsigned int u3 = ylp[s3 * 64 + lane];
    unsigned int u4 = ylp[s4 * 64 + lane];
    unsigned int u5 = ylp[s5 * 64 + lane];
    unsigned int u6 = ylp[s6 * 64 + lane];
    unsigned int u7 = ylp[s7 * 64 + lane];
    ax0 += bflo(u0); ay0 += bfhi(u0);
    ax1 += bflo(u1); ay1 += bfhi(u1);
    ax2 += bflo(u2); ay2 += bfhi(u2);
    ax3 += bflo(u3); ay3 += bfhi(u3);
    ax0 += bflo(u4); ay0 += bfhi(u4);
    ax1 += bflo(u5); ay1 += bfhi(u5);
    ax2 += bflo(u6); ay2 += bfhi(u6);
    ax3 += bflo(u7); ay3 += bfhi(u7);
  }
  for (; e < end; e++) {
    int s = csr[e];
    unsigned int u = ylp[s * 64 + lane];
    ax0 += bflo(u); ay0 += bfhi(u);
  }
  float sc = invd[wid];
  unsigned int rv = ((const unsigned int*)yr)[wid * 64 + lane];
  float vx = ((ax0 + ax1) + (ax2 + ax3)) * sc + bflo(rv);
  float vy = ((ay0 + ay1) + (ay2 + ay3)) * sc + bfhi(rv);
  if (relu) { vx = fmaxf(vx, 0.f); vy = fmaxf(vy, 0.f); }
  ((unsigned int*)out)[wid * 64 + lane] =
      (unsigned int)f2bf(vx) | ((unsigned int)f2bf(vy) << 16);
}

// ---------------- 32-dim aggregation + bias(already in yr) + log_softmax ----------------
__global__ __launch_bounds__(256) void k_agg32_lsm(
    const unsigned short* __restrict__ yl, const unsigned short* __restrict__ yr,
    const int* __restrict__ off, const int* __restrict__ csr,
    const float* __restrict__ invd, float* __restrict__ out) {
  int row  = (blockIdx.x * 256 + threadIdx.x) >> 5;
  int lane = threadIdx.x & 31;
  if (row >= NN) return;
  int beg = off[row], end = off[row + 1];
  float a0 = 0.f, a1 = 0.f, a2 = 0.f, a3 = 0.f;
  int e = beg;
  for (; e + 3 < end; e += 4) {
    int s0 = csr[e], s1 = csr[e + 1], s2 = csr[e + 2], s3 = csr[e + 3];
    a0 += bf1(yl[s0 * 32 + lane]);
    a1 += bf1(yl[s1 * 32 + lane]);
    a2 += bf1(yl[s2 * 32 + lane]);
    a3 += bf1(yl[s3 * 32 + lane]);
  }
  for (; e < end; e++) a0 += bf1(yl[csr[e] * 32 + lane]);
  float v = ((a0 + a1) + (a2 + a3)) * invd[row] + bf1(yr[row * 32 + lane]);
  float m = v;
  #pragma unroll
  for (int o = 16; o; o >>= 1) m = fmaxf(m, __shfl_xor(m, o, 32));
  float ex = expf(v - m);
  float s = ex;
  #pragma unroll
  for (int o = 16; o; o >>= 1) s += __shfl_xor(s, o, 32);
  out[row * 32 + lane] = v - m - logf(s);
}

// ---------------- launch ----------------

extern "C" void kernel_launch(void* const* d_in, const int* in_sizes, int n_in,
                              void* d_out, int out_size, void* d_ws, size_t ws_size,
                              hipStream_t stream) {
  (void)in_sizes; (void)n_in; (void)out_size; (void)ws_size;
  const float* x   = (const float*)d_in[0];
  const int*   ei  = (const int*)d_in[1];
  const float* Wl0 = (const float*)d_in[2];
  const float* bl0 = (const float*)d_in[3];
  const float* Wr0 = (const float*)d_in[4];
  const float* Wl1 = (const float*)d_in[5];
  const float* bl1 = (const float*)d_in[6];
  const float* Wr1 = (const float*)d_in[7];
  const float* Wl2 = (const float*)d_in[8];
  const float* bl2 = (const float*)d_in[9];
  const float* Wr2 = (const float*)d_in[10];
  const int* srcI = ei;
  const int* dstI = ei + NE;

  char* w = (char*)d_ws;
  int*   ccnt   = (int*)(w + 0);                                // 391
  int*   ccur   = (int*)(w + (16 << 10));                       // 391
  int*   cboff  = (int*)(w + (32 << 10));                       // 392
  unsigned short* B0 = (unsigned short*)(w + (64 << 10));       // 64 KB
  unsigned short* B1 = (unsigned short*)(w + (160 << 10));      // 64 KB
  unsigned short* B2 = (unsigned short*)(w + (256 << 10));      // 16 KB
  int*   csroff = (int*)(w + (512 << 10));                      // 400 KB
  float* invd   = (float*)(w + (1024 << 10));                   // 400 KB
  unsigned int* ebuf = (unsigned int*)(w + (size_t)(2) * 1024 * 1024);   // 6.4 MB
  int*   csrsrc = (int*)(w + (size_t)(9) * 1024 * 1024);                 // 6.4 MB
  unsigned short* ylb = (unsigned short*)(w + (size_t)(16) * 1024 * 1024); // 25.6 MB
  unsigned short* yrb = (unsigned short*)(w + (size_t)(48) * 1024 * 1024); // 25.6 MB
  unsigned short* hb  = (unsigned short*)(w + (size_t)(80) * 1024 * 1024); // 25.6 MB

  hipMemsetAsync(ccnt, 0, NCB * sizeof(int), stream);
  hipMemsetAsync(ccur, 0, NCB * sizeof(int), stream);

  // CSR build
  k_chist<<<128, 512, 0, stream>>>(dstI, ccnt);
  k_cscan<<<1, 512, 0, stream>>>(ccnt, cboff, csroff);
  k_cscatter<<<(NE + EB - 1) / EB, SCT, 0, stream>>>(srcI, dstI, cboff, ccur, ebuf);
  k_crefine<<<NCB, 256, 0, stream>>>(ebuf, cboff, csroff, invd, csrsrc);

  // weight prep (bf16, [n][k] layout)
  k_wprep<<<(2 * 128 * 128 + 255) / 256, 256, 0, stream>>>(Wl0, Wr0, 128, B0);
  k_wprep<<<(2 * 128 * 128 + 255) / 256, 256, 0, stream>>>(Wl1, Wr1, 128, B1);
  k_wprep<<<(2 * 32 * 128 + 255) / 256, 256, 0, stream>>>(Wl2, Wr2, 32, B2);

  dim3 gg((NN + 127) / 128);   // 782
  // layer 0 (A = fp32 x, converted during staging)
  k_mgemm<256, 1><<<gg, 512, 0, stream>>>(x, B0, bl0, ylb, yrb);
  k_agg128<<<(NN * 64) / 256, 256, 0, stream>>>(ylb, yrb, csroff, csrsrc, invd, hb, 1);
  // layer 1 (A = bf16 hb)
  k_mgemm<256, 0><<<gg, 512, 0, stream>>>(hb, B1, bl1, ylb, yrb);
  k_agg128<<<(NN * 64) / 256, 256, 0, stream>>>(ylb, yrb, csroff, csrsrc, invd, hb, 1);
  // layer 2 (transform-first, 32-dim) + fused log_softmax
  k_mgemm<64, 0><<<gg, 512, 0, stream>>>(hb, B2, bl2, ylb, yrb);
  k_agg32_lsm<<<(NN * 32) / 256, 256, 0, stream>>>(ylb, yrb, csroff, csrsrc, invd,
                                                   (float*)d_out);
}